// Round 11
// baseline (2983.826 us; speedup 1.0000x reference)
//
#include <hip/hip_runtime.h>
#include <hip/hip_bf16.h>

constexpr int F = 128, H1 = 64, H2 = 32, K11 = 3;
constexpr int BSH = 5;                 // 32 rows per bin
constexpr int BINR = 32;
constexpr int PARTE = 2048;            // edges per partition block
constexpr int MAXBINS = 2048;          // per-array bin cap (N<=65536)

// ---- bf16 helpers ----
static __device__ __forceinline__ float bf_lo(unsigned u) { return __uint_as_float(u << 16); }
static __device__ __forceinline__ float bf_hi(unsigned u) { return __uint_as_float(u & 0xffff0000u); }
static __device__ __forceinline__ unsigned pack_bf16(float a, float b) {
    unsigned ua = __float_as_uint(a), ub = __float_as_uint(b);
    unsigned ra = (ua + 0x7fffu + ((ua >> 16) & 1u)) >> 16;
    unsigned rb = (ub + 0x7fffu + ((ub >> 16) & 1u)) & 0xffff0000u;
    return ra | rb;
}

// ---------------- batched dense GEMM: one launch per layer, 6 jobs via blockIdx.y ----------------
struct GemmB6 { const void* A[6]; const float* W[6]; long long cOff[6]; int M[6]; };

template<int FF, int HH, bool ABF16>
__launch_bounds__(256)
__global__ void gemm_b6_kernel(GemmB6 gb, ushort* __restrict__ Cb) {
    const int y = blockIdx.y;
    const int M = gb.M[y];
    if (blockIdx.x * 64 >= M) return;          // uniform per block: safe before barrier
    const float* __restrict__ W = gb.W[y];
    const void* __restrict__ Av = gb.A[y];
    ushort* C = Cb + gb.cOff[y];
    __shared__ float Ws[FF * HH];
    const int tid = threadIdx.x;
    for (int i = tid * 4; i < FF * HH; i += 1024)
        *reinterpret_cast<float4*>(&Ws[i]) = *reinterpret_cast<const float4*>(&W[i]);
    __syncthreads();

    constexpr int TPR = 4;
    constexpr int CPT = HH / TPR;
    const int t = blockIdx.x * 256 + tid;
    const int row = t / TPR;
    const int sub = t % TPR;
    if (row >= M) return;

    float acc[CPT];
#pragma unroll
    for (int j = 0; j < CPT; ++j) acc[j] = 0.f;

    for (int k = 0; k < FF; k += 8) {
        float av[8];
        if (ABF16) {
            const uint4 u = *reinterpret_cast<const uint4*>((const ushort*)Av + (size_t)row * FF + k);
            av[0] = bf_lo(u.x); av[1] = bf_hi(u.x);
            av[2] = bf_lo(u.y); av[3] = bf_hi(u.y);
            av[4] = bf_lo(u.z); av[5] = bf_hi(u.z);
            av[6] = bf_lo(u.w); av[7] = bf_hi(u.w);
        } else {
            const float* A = (const float*)Av + (size_t)row * FF + k;
            const float4 u0 = *reinterpret_cast<const float4*>(A);
            const float4 u1 = *reinterpret_cast<const float4*>(A + 4);
            av[0] = u0.x; av[1] = u0.y; av[2] = u0.z; av[3] = u0.w;
            av[4] = u1.x; av[5] = u1.y; av[6] = u1.z; av[7] = u1.w;
        }
#pragma unroll
        for (int kk = 0; kk < 8; ++kk) {
            const float* wr = &Ws[(k + kk) * HH + sub * CPT];
#pragma unroll
            for (int j = 0; j < CPT; j += 4) {
                const float4 wv = *reinterpret_cast<const float4*>(&wr[j]);
                acc[j + 0] = fmaf(av[kk], wv.x, acc[j + 0]);
                acc[j + 1] = fmaf(av[kk], wv.y, acc[j + 1]);
                acc[j + 2] = fmaf(av[kk], wv.z, acc[j + 2]);
                acc[j + 3] = fmaf(av[kk], wv.w, acc[j + 3]);
            }
        }
    }
    unsigned packed[CPT / 2];
#pragma unroll
    for (int j = 0; j < CPT; j += 2) packed[j / 2] = pack_bf16(acc[j], acc[j + 1]);
    unsigned* c = (unsigned*)(C + (size_t)row * HH + sub * CPT);
#pragma unroll
    for (int j = 0; j < CPT / 2; j += 4)
        *reinterpret_cast<uint4*>(&c[j]) = make_uint4(packed[j], packed[j + 1], packed[j + 2], packed[j + 3]);
}

// ---------------- build: bin histogram -> scan -> bin-grouped partition (NO finalize) ----------------
struct ArrD {
    const int* rows[6]; const int* cols[6]; const float* vals[6];
    int E[6]; int n[6]; int binBase[6]; int nbins[6];
};

__launch_bounds__(256)
__global__ void binhist_kernel(ArrD d, int* __restrict__ binCnt) {
    const int a = blockIdx.y;
    const int E = d.E[a];
    const int start = blockIdx.x * 8192;
    if (start >= E) return;
    const int nb = d.nbins[a];
    __shared__ int h[MAXBINS];
    for (int i = threadIdx.x; i < nb; i += 256) h[i] = 0;
    __syncthreads();
    const int* rows = d.rows[a];
    const int end = min(E, start + 8192);
    for (int e = start + (int)threadIdx.x; e < end; e += 256)
        atomicAdd(&h[rows[e] >> BSH], 1);
    __syncthreads();
    int* bc = binCnt + d.binBase[a];
    for (int i = threadIdx.x; i < nb; i += 256)
        if (h[i]) atomicAdd(&bc[i], h[i]);
}

__launch_bounds__(256)
__global__ void binscan_kernel(const int* __restrict__ binCnt, int* __restrict__ binPtr,
                               int* __restrict__ binCur, int TB, int Etot) {
    __shared__ int lds[256];
    __shared__ int carry;
    if (threadIdx.x == 0) carry = 0;
    __syncthreads();
    for (int base = 0; base < TB; base += 256) {
        const int i = base + threadIdx.x;
        const int v = (i < TB) ? binCnt[i] : 0;
        lds[threadIdx.x] = v;
        __syncthreads();
        for (int o = 1; o < 256; o <<= 1) {
            int t = (threadIdx.x >= o) ? lds[threadIdx.x - o] : 0;
            __syncthreads();
            lds[threadIdx.x] += t;
            __syncthreads();
        }
        const int c = carry;
        __syncthreads();
        if (i < TB) {
            const int excl = c + lds[threadIdx.x] - v;
            binPtr[i] = excl;
            binCur[i] = excl;
        }
        if (threadIdx.x == 255) carry = c + lds[255];
        __syncthreads();
    }
    if (threadIdx.x == 0) binPtr[TB] = Etot;
}

// partition edges into bin-grouped tmp at GLOBAL positions; tmp entry = (row5|col16, f32 val)
__launch_bounds__(256)
__global__ void partition_all_kernel(ArrD d, int* __restrict__ binCur,
                                     uint2* __restrict__ tmp) {
    const int a = blockIdx.y;
    const int E = d.E[a];
    const int start = blockIdx.x * PARTE;
    if (start >= E) return;
    const int nbins = d.nbins[a];
    const int* __restrict__ rows = d.rows[a];
    const int* __restrict__ cols = d.cols[a];
    const float* __restrict__ vals = d.vals[a];
    int* __restrict__ bc = binCur + d.binBase[a];
    __shared__ int h[MAXBINS];
    __shared__ int base[MAXBINS];
    for (int i = threadIdx.x; i < nbins; i += 256) h[i] = 0;
    __syncthreads();
    int r[PARTE / 256];
#pragma unroll
    for (int j = 0; j < PARTE / 256; ++j) {
        const int idx = start + j * 256 + (int)threadIdx.x;
        r[j] = (idx < E) ? rows[idx] : -1;
        if (r[j] >= 0) atomicAdd(&h[r[j] >> BSH], 1);
    }
    __syncthreads();
    for (int i = threadIdx.x; i < nbins; i += 256) {
        const int c = h[i];
        base[i] = c ? atomicAdd(&bc[i], c) : 0;
    }
    __syncthreads();
    for (int i = threadIdx.x; i < nbins; i += 256) h[i] = 0;
    __syncthreads();
#pragma unroll
    for (int j = 0; j < PARTE / 256; ++j) {
        if (r[j] >= 0) {
            const int idx = start + j * 256 + (int)threadIdx.x;
            const int b = r[j] >> BSH;
            const int p = atomicAdd(&h[b], 1);
            tmp[(size_t)(base[b] + p)] =
                make_uint2(((unsigned)(r[j] & (BINR - 1)) << 16) | (unsigned)cols[idx],
                           __float_as_uint(vals[idx]));
        }
    }
}

// ---------------- SpMM: block per output bin, LDS f32 accumulate ----------------
struct SBin {
    int nb1, n0, n1;
    int gb0[2], gb1[4];          // global bin bases per segment
    const ushort* X0[2];
    const ushort* X1[4];
};

template<int HH, bool RELU, bool YF32>
__launch_bounds__(256)
__global__ void spmm_bin_kernel(SBin d, const uint2* __restrict__ tmp,
                                const int* __restrict__ binPtr,
                                void* __restrict__ Y0, void* __restrict__ Y1) {
    constexpr int LPR = HH / 4;        // uint2 lanes per row: H1=16, H2=8
    constexpr int NSLOT = 256 / LPR;   // edges in parallel per block: 16 / 32
    constexpr int UD = 4;
    __shared__ float acc[BINR][HH];
    const int tid = threadIdx.x;
    const int slot = tid / LPR;
    const int c = tid % LPR;
    float* af = &acc[0][0];
    for (int i = tid; i < BINR * HH; i += 256) af[i] = 0.f;
    __syncthreads();

    const bool isH1 = (int)blockIdx.x < d.nb1;
    int b, nseg;
    int gb[4]; const uint2* X[4];
    if (isH1) {
        b = blockIdx.x; nseg = 4;
#pragma unroll
        for (int k = 0; k < 4; ++k) { gb[k] = d.gb1[k] + b; X[k] = (const uint2*)d.X1[k]; }
    } else {
        b = blockIdx.x - d.nb1; nseg = 2;
        gb[0] = d.gb0[0] + b; X[0] = (const uint2*)d.X0[0];
        gb[1] = d.gb0[1] + b; X[1] = (const uint2*)d.X0[1];
        gb[2] = gb[1]; X[2] = X[1]; gb[3] = gb[1]; X[3] = X[1];
    }

#pragma unroll
    for (int sg = 0; sg < 4; ++sg) {
        if (sg < nseg) {
            const int lo = binPtr[gb[sg]], hi = binPtr[gb[sg] + 1];
            const uint2* __restrict__ Xs = X[sg];
            int i = lo + slot;
            for (; i + (UD - 1) * NSLOT < hi; i += UD * NSLOT) {
                uint2 t[UD], x[UD];
#pragma unroll
                for (int j = 0; j < UD; ++j) t[j] = tmp[i + j * NSLOT];
#pragma unroll
                for (int j = 0; j < UD; ++j) x[j] = Xs[(size_t)(t[j].x & 0xffffu) * LPR + c];
#pragma unroll
                for (int j = 0; j < UD; ++j) {
                    const int row = (int)(t[j].x >> 16);
                    const float v = __uint_as_float(t[j].y);
                    atomicAdd(&acc[row][c * 4 + 0], v * bf_lo(x[j].x));
                    atomicAdd(&acc[row][c * 4 + 1], v * bf_hi(x[j].x));
                    atomicAdd(&acc[row][c * 4 + 2], v * bf_lo(x[j].y));
                    atomicAdd(&acc[row][c * 4 + 3], v * bf_hi(x[j].y));
                }
            }
            for (; i < hi; i += NSLOT) {
                const uint2 t = tmp[i];
                const uint2 x = Xs[(size_t)(t.x & 0xffffu) * LPR + c];
                const int row = (int)(t.x >> 16);
                const float v = __uint_as_float(t.y);
                atomicAdd(&acc[row][c * 4 + 0], v * bf_lo(x.x));
                atomicAdd(&acc[row][c * 4 + 1], v * bf_hi(x.x));
                atomicAdd(&acc[row][c * 4 + 2], v * bf_lo(x.y));
                atomicAdd(&acc[row][c * 4 + 3], v * bf_hi(x.y));
            }
        }
    }
    __syncthreads();

    // write out: each thread handles 8 (H1) / 4 (H2) contiguous cols of one row
    const int r0 = b * BINR;
    const int nrows = (isH1 ? d.n1 : d.n0) - r0;
    const int row = tid >> 3;           // 0..31
    const int cg = tid & 7;             // 0..7
    if (row < nrows) {
        if (YF32) {
            // HH=32: 8 groups x 4 floats
            float4 v;
            v.x = acc[row][cg * 4 + 0]; v.y = acc[row][cg * 4 + 1];
            v.z = acc[row][cg * 4 + 2]; v.w = acc[row][cg * 4 + 3];
            if (RELU) { v.x = fmaxf(v.x, 0.f); v.y = fmaxf(v.y, 0.f); v.z = fmaxf(v.z, 0.f); v.w = fmaxf(v.w, 0.f); }
            float* y = (isH1 ? (float*)Y1 : (float*)Y0) + (size_t)(r0 + row) * HH + cg * 4;
            *reinterpret_cast<float4*>(y) = v;
        } else {
            // HH=64: 8 groups x 8 cols -> 4 packed words
            float rv[8];
#pragma unroll
            for (int q = 0; q < 8; ++q) {
                float f = acc[row][cg * 8 + q];
                rv[q] = RELU ? fmaxf(f, 0.f) : f;
            }
            uint4 w = make_uint4(pack_bf16(rv[0], rv[1]), pack_bf16(rv[2], rv[3]),
                                 pack_bf16(rv[4], rv[5]), pack_bf16(rv[6], rv[7]));
            ushort* y = (isH1 ? (ushort*)Y1 : (ushort*)Y0) + (size_t)(r0 + row) * HH + cg * 8;
            *reinterpret_cast<uint4*>(y) = w;
        }
    }
}

extern "C" void kernel_launch(void* const* d_in, const int* in_sizes, int n_in,
                              void* d_out, int out_size, void* d_ws, size_t ws_size,
                              hipStream_t stream) {
    const float* feat0 = (const float*)d_in[0];
    const float* feat1 = (const float*)d_in[1];
    const int*   e00_row = (const int*)d_in[2];
    const int*   e00_col = (const int*)d_in[3];
    const float* e00_val = (const float*)d_in[4];
    const int*   e01_row = (const int*)d_in[5];
    const int*   e01_col = (const int*)d_in[6];
    const float* e01_val = (const float*)d_in[7];
    const int*   e10_row = (const int*)d_in[8];
    const int*   e10_col = (const int*)d_in[9];
    const float* e10_val = (const float*)d_in[10];
    const int*   e11_row = (const int*)d_in[11];
    const int*   e11_col = (const int*)d_in[12];
    const float* e11_val = (const float*)d_in[13];
    const float* W1_00 = (const float*)d_in[14];
    const float* W1_01 = (const float*)d_in[15];
    const float* W1_10 = (const float*)d_in[16];
    const float* W1_11 = (const float*)d_in[17];
    const float* W2_00 = (const float*)d_in[18];
    const float* W2_01 = (const float*)d_in[19];
    const float* W2_10 = (const float*)d_in[20];
    const float* W2_11 = (const float*)d_in[21];

    const int N0  = in_sizes[0] / F;
    const int N1  = in_sizes[1] / F;
    const int E00 = in_sizes[2];
    const int E01 = in_sizes[5];
    const int E10 = in_sizes[8];
    const int E11 = in_sizes[11] / K11;
    const long long E_total = (long long)E00 + E01 + E10 + (long long)K11 * E11;

    struct HA { const int* rows; const int* cols; const float* vals; int E; int n; };
    const HA arrs[6] = {
        {e00_row, e00_col, e00_val, E00, N0},
        {e01_row, e01_col, e01_val, E01, N0},
        {e10_row, e10_col, e10_val, E10, N1},
        {e11_row,          e11_col,          e11_val,          E11, N1},
        {e11_row + E11,    e11_col + E11,    e11_val + E11,    E11, N1},
        {e11_row + 2*E11,  e11_col + 2*E11,  e11_val + 2*E11,  E11, N1},
    };

    int nbins_[6], binBase_[6];
    int TB = 0, maxE = 0, maxNB = 0;
    for (int i = 0; i < 6; ++i) {
        binBase_[i] = TB; nbins_[i] = (arrs[i].n + BINR - 1) >> BSH; TB += nbins_[i];
        maxE = max(maxE, arrs[i].E); maxNB = max(maxNB, nbins_[i]);
    }
    const int TBc = (TB + 1 + 3) & ~3;   // binPtr needs TB+1; keep tmp 8B-aligned

    // ---- workspace layout ----
    ushort* h0 = (ushort*)d_ws;                       // N0*H1 bf16
    ushort* h1 = h0 + (size_t)N0 * H1;                // N1*H1 bf16
    ushort* g  = h1 + (size_t)N1 * H1;                // (2N0+4N1)*H1 bf16 stage buffer
    const size_t G = ((size_t)2 * N0 + 4 * N1) * H1;
    int* iw = (int*)(g + G);
    int* binCnt = iw;
    int* binPtr = binCnt + TBc;
    int* binCur = binPtr + TBc;
    uint2* tmp  = (uint2*)(binCur + TBc);             // E_total entries, persists both layers

    const size_t required = ((size_t)(N0 + N1) * H1 + G) * 2
                          + (size_t)3 * TBc * 4 + (size_t)E_total * 8;
    if (ws_size < required || N0 > 65536 || N1 > 65536 || maxNB > MAXBINS) return;

    // -------- build --------
    hipMemsetAsync(binCnt, 0, (size_t)TBc * sizeof(int), stream);
    ArrD ad;
    for (int i = 0; i < 6; ++i) {
        ad.rows[i] = arrs[i].rows; ad.cols[i] = arrs[i].cols; ad.vals[i] = arrs[i].vals;
        ad.E[i] = arrs[i].E; ad.n[i] = arrs[i].n; ad.binBase[i] = binBase_[i]; ad.nbins[i] = nbins_[i];
    }
    binhist_kernel<<<dim3((maxE + 8191) / 8192, 6), 256, 0, stream>>>(ad, binCnt);
    binscan_kernel<<<1, 256, 0, stream>>>(binCnt, binPtr, binCur, TB, (int)E_total);
    partition_all_kernel<<<dim3((maxE + PARTE - 1) / PARTE, 6), 256, 0, stream>>>(ad, binCur, tmp);

    // -------- main sequence --------
    float* z0 = (float*)d_out;
    float* z1 = (float*)d_out + (size_t)N0 * H2;
    const int gx1 = (max(N0, N1) * 4 + 255) / 256;
    const int nb0 = nbins_[0], nb1 = nbins_[2];

    // layer 1 GEMMs: g rows = [A(N0) | B(N1) | C(N0) | D0(N1) D1(N1) D2(N1)]
    {
        GemmB6 gb;
        gb.A[0] = feat0; gb.W[0] = W1_00; gb.cOff[0] = 0;                                   gb.M[0] = N0;
        gb.A[1] = feat0; gb.W[1] = W1_10; gb.cOff[1] = (long long)(N0 + N1) * H1;           gb.M[1] = N0;
        gb.A[2] = feat1; gb.W[2] = W1_01; gb.cOff[2] = (long long)N0 * H1;                  gb.M[2] = N1;
        for (int k = 0; k < K11; ++k) {
            gb.A[3 + k] = feat1; gb.W[3 + k] = W1_11 + (size_t)k * F * H1;
            gb.cOff[3 + k] = ((long long)(2 * N0 + N1) + (long long)k * N1) * H1;           gb.M[3 + k] = N1;
        }
        gemm_b6_kernel<F, H1, false><<<dim3(gx1, 6), 256, 0, stream>>>(gb, g);
    }
    // layer 1 SpMM (bin-LDS, h1 bins first)
    {
        SBin sb;
        sb.nb1 = nb1; sb.n0 = N0; sb.n1 = N1;
        sb.gb0[0] = binBase_[0]; sb.X0[0] = g;
        sb.gb0[1] = binBase_[1]; sb.X0[1] = g + (size_t)N0 * H1;
        sb.gb1[0] = binBase_[2]; sb.X1[0] = g + (size_t)(N0 + N1) * H1;
        for (int k = 0; k < K11; ++k) {
            sb.gb1[1 + k] = binBase_[3 + k];
            sb.X1[1 + k] = g + ((size_t)(2 * N0 + N1) + (size_t)k * N1) * H1;
        }
        spmm_bin_kernel<H1, true, false><<<nb1 + nb0, 256, 0, stream>>>(sb, tmp, binPtr, h0, h1);
    }
    // layer 2 GEMMs (A = h0 / h1, bf16)
    {
        GemmB6 gb;
        gb.A[0] = h0; gb.W[0] = W2_00; gb.cOff[0] = 0;                                      gb.M[0] = N0;
        gb.A[1] = h0; gb.W[1] = W2_10; gb.cOff[1] = (long long)(N0 + N1) * H2;              gb.M[1] = N0;
        gb.A[2] = h1; gb.W[2] = W2_01; gb.cOff[2] = (long long)N0 * H2;                     gb.M[2] = N1;
        for (int k = 0; k < K11; ++k) {
            gb.A[3 + k] = h1; gb.W[3 + k] = W2_11 + (size_t)k * H1 * H2;
            gb.cOff[3 + k] = ((long long)(2 * N0 + N1) + (long long)k * N1) * H2;           gb.M[3 + k] = N1;
        }
        gemm_b6_kernel<H1, H2, true><<<dim3(gx1, 6), 256, 0, stream>>>(gb, g);
    }
    // layer 2 SpMM (bin-LDS, f32 out)
    {
        SBin sb;
        sb.nb1 = nb1; sb.n0 = N0; sb.n1 = N1;
        sb.gb0[0] = binBase_[0]; sb.X0[0] = (const ushort*)g;
        sb.gb0[1] = binBase_[1]; sb.X0[1] = g + (size_t)N0 * H2;
        sb.gb1[0] = binBase_[2]; sb.X1[0] = g + (size_t)(N0 + N1) * H2;
        for (int k = 0; k < K11; ++k) {
            sb.gb1[1 + k] = binBase_[3 + k];
            sb.X1[1 + k] = g + ((size_t)(2 * N0 + N1) + (size_t)k * N1) * H2;
        }
        spmm_bin_kernel<H2, false, true><<<nb1 + nb0, 256, 0, stream>>>(sb, tmp, binPtr, z0, z1);
    }

    (void)n_in; (void)out_size;
}

// Round 12
// 419.361 us; speedup vs baseline: 7.1152x; 7.1152x over previous
//
#include <hip/hip_runtime.h>
#include <hip/hip_bf16.h>

constexpr int F = 128, H1 = 64, H2 = 32, K11 = 3;
constexpr int BSH = 6;                 // 64 rows per bin
constexpr int PARTE = 2048;            // edges per partition block

// ---- bf16 helpers ----
static __device__ __forceinline__ float bf_lo(unsigned u) { return __uint_as_float(u << 16); }
static __device__ __forceinline__ float bf_hi(unsigned u) { return __uint_as_float(u & 0xffff0000u); }
static __device__ __forceinline__ unsigned bf16_1(float a) {     // low-16 bf16 (RNE)
    unsigned ua = __float_as_uint(a);
    return (ua + 0x7fffu + ((ua >> 16) & 1u)) >> 16;
}
static __device__ __forceinline__ unsigned pack_bf16(float a, float b) {
    unsigned ua = __float_as_uint(a), ub = __float_as_uint(b);
    unsigned ra = (ua + 0x7fffu + ((ua >> 16) & 1u)) >> 16;
    unsigned rb = (ub + 0x7fffu + ((ub >> 16) & 1u)) & 0xffff0000u;
    return ra | rb;
}

// ---------------- batched dense GEMM: C_y[M x HH](bf16) = A[M x FF] @ W_y[FF x HH] ----------------
struct GemmB { const float* W[4]; long long cOff[4]; };

template<int FF, int HH, bool ABF16>
__launch_bounds__(256)
__global__ void gemm_b_kernel(const void* __restrict__ Av, GemmB gb,
                              ushort* __restrict__ Cb, int M) {
    const float* __restrict__ W = gb.W[blockIdx.y];
    ushort* C = Cb + gb.cOff[blockIdx.y];
    __shared__ float Ws[FF * HH];
    const int tid = threadIdx.x;
    for (int i = tid * 4; i < FF * HH; i += 1024)
        *reinterpret_cast<float4*>(&Ws[i]) = *reinterpret_cast<const float4*>(&W[i]);
    __syncthreads();

    constexpr int TPR = 4;
    constexpr int CPT = HH / TPR;
    const int t = blockIdx.x * 256 + tid;
    const int row = t / TPR;
    const int sub = t % TPR;
    if (row >= M) return;

    float acc[CPT];
#pragma unroll
    for (int j = 0; j < CPT; ++j) acc[j] = 0.f;

    for (int k = 0; k < FF; k += 8) {
        float av[8];
        if (ABF16) {
            const uint4 u = *reinterpret_cast<const uint4*>((const ushort*)Av + (size_t)row * FF + k);
            av[0] = bf_lo(u.x); av[1] = bf_hi(u.x);
            av[2] = bf_lo(u.y); av[3] = bf_hi(u.y);
            av[4] = bf_lo(u.z); av[5] = bf_hi(u.z);
            av[6] = bf_lo(u.w); av[7] = bf_hi(u.w);
        } else {
            const float* A = (const float*)Av + (size_t)row * FF + k;
            const float4 u0 = *reinterpret_cast<const float4*>(A);
            const float4 u1 = *reinterpret_cast<const float4*>(A + 4);
            av[0] = u0.x; av[1] = u0.y; av[2] = u0.z; av[3] = u0.w;
            av[4] = u1.x; av[5] = u1.y; av[6] = u1.z; av[7] = u1.w;
        }
#pragma unroll
        for (int kk = 0; kk < 8; ++kk) {
            const float* wr = &Ws[(k + kk) * HH + sub * CPT];
#pragma unroll
            for (int j = 0; j < CPT; j += 4) {
                const float4 wv = *reinterpret_cast<const float4*>(&wr[j]);
                acc[j + 0] = fmaf(av[kk], wv.x, acc[j + 0]);
                acc[j + 1] = fmaf(av[kk], wv.y, acc[j + 1]);
                acc[j + 2] = fmaf(av[kk], wv.z, acc[j + 2]);
                acc[j + 3] = fmaf(av[kk], wv.w, acc[j + 3]);
            }
        }
    }
    unsigned packed[CPT / 2];
#pragma unroll
    for (int j = 0; j < CPT; j += 2) packed[j / 2] = pack_bf16(acc[j], acc[j + 1]);
    unsigned* c = (unsigned*)(C + (size_t)row * HH + sub * CPT);
#pragma unroll
    for (int j = 0; j < CPT / 2; j += 4)
        *reinterpret_cast<uint4*>(&c[j]) = make_uint4(packed[j], packed[j + 1], packed[j + 2], packed[j + 3]);
}

// ---------------- CSR build: two-level bin partition (64-row bins) ----------------
struct BinDesc { const int* rows[6]; int E[6]; int n[6]; int binBase[6]; };

__launch_bounds__(256)
__global__ void binhist_kernel(BinDesc d, int* __restrict__ binCnt) {
    const int a = blockIdx.y;
    const int E = d.E[a];
    const int start = blockIdx.x * 8192;
    if (start >= E) return;
    const int nb = (d.n[a] + 63) >> BSH;        // <= 1024
    __shared__ int h[1024];
    for (int i = threadIdx.x; i < nb; i += 256) h[i] = 0;
    __syncthreads();
    const int* rows = d.rows[a];
    const int end = min(E, start + 8192);
    for (int e = start + (int)threadIdx.x; e < end; e += 256)
        atomicAdd(&h[rows[e] >> BSH], 1);
    __syncthreads();
    int* bc = binCnt + d.binBase[a];
    for (int i = threadIdx.x; i < nb; i += 256)
        if (h[i]) atomicAdd(&bc[i], h[i]);
}

__launch_bounds__(256)
__global__ void binscan_kernel(const int* __restrict__ binCnt, int* __restrict__ binPtr,
                               int* __restrict__ binCur, int TB, int Etot,
                               int* __restrict__ gptr, int Lidx) {
    __shared__ int lds[256];
    __shared__ int carry;
    if (threadIdx.x == 0) carry = 0;
    __syncthreads();
    for (int base = 0; base < TB; base += 256) {
        const int i = base + threadIdx.x;
        const int v = (i < TB) ? binCnt[i] : 0;
        lds[threadIdx.x] = v;
        __syncthreads();
        for (int o = 1; o < 256; o <<= 1) {
            int t = (threadIdx.x >= o) ? lds[threadIdx.x - o] : 0;
            __syncthreads();
            lds[threadIdx.x] += t;
            __syncthreads();
        }
        const int c = carry;
        __syncthreads();
        if (i < TB) {
            const int excl = c + lds[threadIdx.x] - v;
            binPtr[i] = excl;
            binCur[i] = excl;
        }
        if (threadIdx.x == 255) carry = c + lds[255];
        __syncthreads();
    }
    if (threadIdx.x == 0) { binPtr[TB] = Etot; gptr[Lidx] = Etot; }
}

struct PartD {
    const int* rows[4]; const int* cols[4]; const float* vals[4];
    int E[4]; int nbins[4]; int binBase[4]; int edgeBase[4];
};

__launch_bounds__(256)
__global__ void partition_all_kernel(PartD d, int* __restrict__ binCur,
                                     uint2* __restrict__ tmp) {
    const int a = blockIdx.y;
    const int E = d.E[a];
    const int start = blockIdx.x * PARTE;
    if (start >= E) return;
    const int nbins = d.nbins[a];
    const int* __restrict__ rows = d.rows[a];
    const int* __restrict__ cols = d.cols[a];
    const float* __restrict__ vals = d.vals[a];
    int* __restrict__ bc = binCur + d.binBase[a];
    const int tmpBase = d.edgeBase[a];
    __shared__ int h[1024];
    __shared__ int base[1024];
    for (int i = threadIdx.x; i < nbins; i += 256) h[i] = 0;
    __syncthreads();
    int r[PARTE / 256];
#pragma unroll
    for (int j = 0; j < PARTE / 256; ++j) {
        const int idx = start + j * 256 + (int)threadIdx.x;
        r[j] = (idx < E) ? rows[idx] : -1;
        if (r[j] >= 0) atomicAdd(&h[r[j] >> BSH], 1);
    }
    __syncthreads();
    for (int i = threadIdx.x; i < nbins; i += 256) {
        const int c = h[i];
        base[i] = c ? atomicAdd(&bc[i], c) : 0;
    }
    __syncthreads();
    for (int i = threadIdx.x; i < nbins; i += 256) h[i] = 0;
    __syncthreads();
#pragma unroll
    for (int j = 0; j < PARTE / 256; ++j) {
        if (r[j] >= 0) {
            const int idx = start + j * 256 + (int)threadIdx.x;
            const int b = r[j] >> BSH;
            const int p = atomicAdd(&h[b], 1);
            tmp[(size_t)(base[b] + p - tmpBase)] =
                make_uint2(((unsigned)(r[j] & 63) << 16) | (unsigned)cols[idx],
                           __float_as_uint(vals[idx]));
        }
    }
}

struct FinD { int binBase[4]; int edgeBase[4]; int n[4]; int rowBase[4]; };

__launch_bounds__(256)
__global__ void finalize_all_kernel(FinD d, const uint2* __restrict__ tmp,
                                    const int* __restrict__ binPtr,
                                    int* __restrict__ gptr, unsigned* __restrict__ cv) {
    const int a = blockIdx.y;
    const int n = d.n[a];
    const int nbins = (n + 63) >> BSH;
    const int b = blockIdx.x;
    if (b >= nbins) return;
    const int* bp = binPtr + d.binBase[a];
    const int binStart = bp[b], binEnd = bp[b + 1];
    const int lo = binStart - d.edgeBase[a], hi = binEnd - d.edgeBase[a];
    __shared__ int cnt[64], off[64], cur[64];
    if (threadIdx.x < 64) cnt[threadIdx.x] = 0;
    __syncthreads();
    for (int i = lo + (int)threadIdx.x; i < hi; i += 256)
        atomicAdd(&cnt[tmp[i].x >> 16], 1);
    __syncthreads();
    if (threadIdx.x < 64) off[threadIdx.x] = cnt[threadIdx.x];
    __syncthreads();
    for (int o = 1; o < 64; o <<= 1) {
        int t = 0;
        if (threadIdx.x < 64 && (int)threadIdx.x >= o) t = off[threadIdx.x - o];
        __syncthreads();
        if (threadIdx.x < 64) off[threadIdx.x] += t;
        __syncthreads();
    }
    const int r0 = b << BSH;
    const int nrows = min(64, n - r0);
    if (threadIdx.x < 64) {
        const int excl = off[threadIdx.x] - cnt[threadIdx.x];
        cur[threadIdx.x] = excl;
        if ((int)threadIdx.x < nrows) (gptr + d.rowBase[a])[r0 + threadIdx.x] = binStart + excl;
    }
    __syncthreads();
    for (int i = lo + (int)threadIdx.x; i < hi; i += 256) {
        const uint2 t = tmp[i];
        const int p = atomicAdd(&cur[t.x >> 16], 1);
        cv[binStart + p] = ((t.x & 0xffffu) << 16) | bf16_1(__uint_as_float(t.y));
    }
}

// ---------------- SpMM v3: wave-per-row, 8B gathers, EPW edges in parallel ----------------
struct SpmmD {
    int n0, nseg0, nseg1;
    int off0[2], off1[4];
    const ushort* X0[2];
    const ushort* X1[4];
};

template<int HH, bool RELU, bool YF32>
__launch_bounds__(256)
__global__ void spmm2_kernel(const int* __restrict__ gptr, SpmmD d,
                             const unsigned* __restrict__ cv,
                             void* __restrict__ Y0, void* __restrict__ Y1,
                             int totalRows) {
    constexpr int LPR = HH / 4;        // lanes per row (uint2 = 4 bf16 each)
    constexpr int EPW = 64 / LPR;      // edges in parallel per wave (H1: 4, H2: 8)
    const int wid = (int)threadIdx.x >> 6;
    const int lane = (int)threadIdx.x & 63;
    const int sub = lane / LPR;        // edge slot
    const int c = lane % LPR;          // uint2 index within row
    const int grow = blockIdx.x * 4 + wid;
    if (grow >= totalRows) return;

    int row, nseg; void* Y;
    int o[4]; const uint2* X[4];
    if (grow < d.n0) {
        row = grow; Y = Y0; nseg = d.nseg0;
        o[0] = d.off0[0]; o[1] = d.off0[1]; o[2] = 0; o[3] = 0;
        X[0] = (const uint2*)d.X0[0]; X[1] = (const uint2*)d.X0[1];
        X[2] = nullptr; X[3] = nullptr;
    } else {
        row = grow - d.n0; Y = Y1; nseg = d.nseg1;
        o[0] = d.off1[0]; o[1] = d.off1[1]; o[2] = d.off1[2]; o[3] = d.off1[3];
        X[0] = (const uint2*)d.X1[0]; X[1] = (const uint2*)d.X1[1];
        X[2] = (const uint2*)d.X1[2]; X[3] = (const uint2*)d.X1[3];
    }

    float4 a0 = {0,0,0,0}, a1 = {0,0,0,0}, a2 = {0,0,0,0}, a3 = {0,0,0,0};
#pragma unroll
    for (int sg = 0; sg < 4; ++sg) {
        if (sg < nseg) {
            const int* p = gptr + o[sg] + row;
            const int s = p[0], e = p[1];
            const uint2* __restrict__ Xs = X[sg];
            int i = s;
            for (; i + 4 * EPW <= e; i += 4 * EPW) {
                const unsigned cw0 = cv[i + 0 * EPW + sub];
                const unsigned cw1 = cv[i + 1 * EPW + sub];
                const unsigned cw2 = cv[i + 2 * EPW + sub];
                const unsigned cw3 = cv[i + 3 * EPW + sub];
                const uint2 x0 = Xs[(size_t)(cw0 >> 16) * LPR + c];
                const uint2 x1 = Xs[(size_t)(cw1 >> 16) * LPR + c];
                const uint2 x2 = Xs[(size_t)(cw2 >> 16) * LPR + c];
                const uint2 x3 = Xs[(size_t)(cw3 >> 16) * LPR + c];
                const float v0 = __uint_as_float(cw0 << 16);
                const float v1 = __uint_as_float(cw1 << 16);
                const float v2 = __uint_as_float(cw2 << 16);
                const float v3 = __uint_as_float(cw3 << 16);
                a0.x = fmaf(v0, bf_lo(x0.x), a0.x); a0.y = fmaf(v0, bf_hi(x0.x), a0.y);
                a0.z = fmaf(v0, bf_lo(x0.y), a0.z); a0.w = fmaf(v0, bf_hi(x0.y), a0.w);
                a1.x = fmaf(v1, bf_lo(x1.x), a1.x); a1.y = fmaf(v1, bf_hi(x1.x), a1.y);
                a1.z = fmaf(v1, bf_lo(x1.y), a1.z); a1.w = fmaf(v1, bf_hi(x1.y), a1.w);
                a2.x = fmaf(v2, bf_lo(x2.x), a2.x); a2.y = fmaf(v2, bf_hi(x2.x), a2.y);
                a2.z = fmaf(v2, bf_lo(x2.y), a2.z); a2.w = fmaf(v2, bf_hi(x2.y), a2.w);
                a3.x = fmaf(v3, bf_lo(x3.x), a3.x); a3.y = fmaf(v3, bf_hi(x3.x), a3.y);
                a3.z = fmaf(v3, bf_lo(x3.y), a3.z); a3.w = fmaf(v3, bf_hi(x3.y), a3.w);
            }
#pragma unroll
            for (int j = 0; j < 4; ++j) {
                const int idx = i + j * EPW + sub;
                if (idx < e) {
                    const unsigned cw = cv[idx];
                    const uint2 x = Xs[(size_t)(cw >> 16) * LPR + c];
                    const float v = __uint_as_float(cw << 16);
                    a0.x = fmaf(v, bf_lo(x.x), a0.x); a0.y = fmaf(v, bf_hi(x.x), a0.y);
                    a0.z = fmaf(v, bf_lo(x.y), a0.z); a0.w = fmaf(v, bf_hi(x.y), a0.w);
                }
            }
        }
    }
    float4 r;
    r.x = (a0.x + a1.x) + (a2.x + a3.x);
    r.y = (a0.y + a1.y) + (a2.y + a3.y);
    r.z = (a0.z + a1.z) + (a2.z + a3.z);
    r.w = (a0.w + a1.w) + (a2.w + a3.w);
#pragma unroll
    for (int off = LPR; off < 64; off <<= 1) {
        r.x += __shfl_xor(r.x, off, 64);
        r.y += __shfl_xor(r.y, off, 64);
        r.z += __shfl_xor(r.z, off, 64);
        r.w += __shfl_xor(r.w, off, 64);
    }
    if (sub == 0) {
        if (RELU) {
            r.x = fmaxf(r.x, 0.f); r.y = fmaxf(r.y, 0.f);
            r.z = fmaxf(r.z, 0.f); r.w = fmaxf(r.w, 0.f);
        }
        if (YF32) {
            *reinterpret_cast<float4*>((float*)Y + (size_t)row * HH + c * 4) = r;
        } else {
            reinterpret_cast<uint2*>((unsigned*)Y + (size_t)row * (HH / 2))[c] =
                make_uint2(pack_bf16(r.x, r.y), pack_bf16(r.z, r.w));
        }
    }
}

extern "C" void kernel_launch(void* const* d_in, const int* in_sizes, int n_in,
                              void* d_out, int out_size, void* d_ws, size_t ws_size,
                              hipStream_t stream) {
    const float* feat0 = (const float*)d_in[0];
    const float* feat1 = (const float*)d_in[1];
    const int*   e00_row = (const int*)d_in[2];
    const int*   e00_col = (const int*)d_in[3];
    const float* e00_val = (const float*)d_in[4];
    const int*   e01_row = (const int*)d_in[5];
    const int*   e01_col = (const int*)d_in[6];
    const float* e01_val = (const float*)d_in[7];
    const int*   e10_row = (const int*)d_in[8];
    const int*   e10_col = (const int*)d_in[9];
    const float* e10_val = (const float*)d_in[10];
    const int*   e11_row = (const int*)d_in[11];
    const int*   e11_col = (const int*)d_in[12];
    const float* e11_val = (const float*)d_in[13];
    const float* W1_00 = (const float*)d_in[14];
    const float* W1_01 = (const float*)d_in[15];
    const float* W1_10 = (const float*)d_in[16];
    const float* W1_11 = (const float*)d_in[17];
    const float* W2_00 = (const float*)d_in[18];
    const float* W2_01 = (const float*)d_in[19];
    const float* W2_10 = (const float*)d_in[20];
    const float* W2_11 = (const float*)d_in[21];

    const int N0  = in_sizes[0] / F;
    const int N1  = in_sizes[1] / F;
    const int E00 = in_sizes[2];
    const int E01 = in_sizes[5];
    const int E10 = in_sizes[8];
    const int E11 = in_sizes[11] / K11;
    const long long E_total = (long long)E00 + E01 + E10 + (long long)K11 * E11;

    const int s00 = 0, s01 = N0, s10 = 2 * N0, s11 = 2 * N0 + N1;
    const int L = 2 * N0 + (1 + K11) * N1;

    struct HA { const int* rows; const int* cols; const float* vals; int E; int s; int n; };
    const HA arrs[6] = {
        {e00_row, e00_col, e00_val, E00, s00, N0},
        {e01_row, e01_col, e01_val, E01, s01, N0},
        {e10_row, e10_col, e10_val, E10, s10, N1},
        {e11_row,          e11_col,          e11_val,          E11, s11,          N1},
        {e11_row + E11,    e11_col + E11,    e11_val + E11,    E11, s11 + N1,     N1},
        {e11_row + 2*E11,  e11_col + 2*E11,  e11_val + 2*E11,  E11, s11 + 2*N1,   N1},
    };

    int nbins_[6], binBase_[6]; long long edgeBase_[6];
    int TB = 0; long long eb = 0;
    int maxE = 0;
    for (int i = 0; i < 6; ++i) {
        binBase_[i] = TB; nbins_[i] = (arrs[i].n + 63) >> BSH; TB += nbins_[i];
        edgeBase_[i] = eb; eb += arrs[i].E;
        maxE = max(maxE, arrs[i].E);
    }
    const int TBc = (TB + 2 + 3) & ~3;
    const int Lc = (L + 1 + 3) & ~3;

    // ---- workspace layout ----
    ushort* h0 = (ushort*)d_ws;                       // N0*H1 bf16
    ushort* h1 = h0 + (size_t)N0 * H1;                // N1*H1 bf16
    ushort* g  = h1 + (size_t)N1 * H1;                // (2N0+4N1)*H1 bf16 stage buffer (aliased by tmp)
    const size_t G = ((size_t)2 * N0 + 4 * N1) * H1;
    int* iw = (int*)(g + G);
    int* binCnt = iw;
    int* binPtr = binCnt + TBc;
    int* binCur = binPtr + TBc;
    int* gptr   = binCur + TBc;
    unsigned* cv = (unsigned*)(gptr + Lc);

    const size_t required = ((size_t)(N0 + N1) * H1 + G) * 2
                          + ((size_t)3 * TBc + Lc + (size_t)E_total) * 4;
    const size_t batchA = ((size_t)E00 + E01) * 8;
    const size_t batchB = ((size_t)E10 + (size_t)K11 * E11) * 8;
    if (ws_size < required || N0 > 65536 || N1 > 65536 ||
        batchA > G * 2 || batchB > G * 2) return;

    // -------- CSR build --------
    hipMemsetAsync(binCnt, 0, (size_t)TBc * sizeof(int), stream);
    BinDesc bd;
    for (int i = 0; i < 6; ++i) { bd.rows[i] = arrs[i].rows; bd.E[i] = arrs[i].E; bd.n[i] = arrs[i].n; bd.binBase[i] = binBase_[i]; }
    binhist_kernel<<<dim3((maxE + 8191) / 8192, 6), 256, 0, stream>>>(bd, binCnt);
    binscan_kernel<<<1, 256, 0, stream>>>(binCnt, binPtr, binCur, TB, (int)E_total, gptr, L);

    uint2* tmp = (uint2*)g;
    auto launchPF = [&](int first, int cnt) {
        const long long tmpBase = edgeBase_[first];
        PartD pd{}; FinD fd{};
        int mE = 0, mNB = 0;
        for (int j = 0; j < cnt; ++j) {
            const int i = first + j;
            pd.rows[j] = arrs[i].rows; pd.cols[j] = arrs[i].cols; pd.vals[j] = arrs[i].vals;
            pd.E[j] = arrs[i].E; pd.nbins[j] = nbins_[i]; pd.binBase[j] = binBase_[i];
            pd.edgeBase[j] = (int)tmpBase;
            fd.binBase[j] = binBase_[i]; fd.edgeBase[j] = (int)tmpBase;
            fd.n[j] = arrs[i].n; fd.rowBase[j] = arrs[i].s;
            mE = max(mE, arrs[i].E); mNB = max(mNB, nbins_[i]);
        }
        partition_all_kernel<<<dim3((mE + PARTE - 1) / PARTE, cnt), 256, 0, stream>>>(pd, binCur, tmp);
        finalize_all_kernel<<<dim3(mNB, cnt), 256, 0, stream>>>(fd, tmp, binPtr, gptr, cv);
    };
    launchPF(0, 2);   // e00 + e01
    launchPF(2, 4);   // e10 + e11 x3

    // -------- main sequence --------
    float* z0 = (float*)d_out;
    float* z1 = (float*)d_out + (size_t)N0 * H2;
    const int TR = N0 + N1;

    // layer 1 GEMMs: g rows = [A(N0) | B(N1) | C(N0) | D0(N1) D1(N1) D2(N1)]
    {
        GemmB ga; ga.W[0] = W1_00; ga.cOff[0] = 0;
        ga.W[1] = W1_10; ga.cOff[1] = (long long)(N0 + N1) * H1;
        ga.W[2] = W1_00; ga.cOff[2] = 0; ga.W[3] = W1_00; ga.cOff[3] = 0;
        gemm_b_kernel<F, H1, false><<<dim3((N0 * 4 + 255) / 256, 2), 256, 0, stream>>>(feat0, ga, g, N0);
        GemmB gbt; gbt.W[0] = W1_01; gbt.cOff[0] = (long long)N0 * H1;
        for (int k = 0; k < K11; ++k) {
            gbt.W[1 + k] = W1_11 + (size_t)k * F * H1;
            gbt.cOff[1 + k] = ((long long)(2 * N0 + N1) + (long long)k * N1) * H1;
        }
        gemm_b_kernel<F, H1, false><<<dim3((N1 * 4 + 255) / 256, 4), 256, 0, stream>>>(feat1, gbt, g, N1);
    }
    // layer 1 SpMM (h0 + h1 fused)
    {
        SpmmD sd;
        sd.n0 = N0; sd.nseg0 = 2; sd.nseg1 = 4;
        sd.off0[0] = s00; sd.X0[0] = g;
        sd.off0[1] = s01; sd.X0[1] = g + (size_t)N0 * H1;
        sd.off1[0] = s10; sd.X1[0] = g + (size_t)(N0 + N1) * H1;
        for (int k = 0; k < K11; ++k) {
            sd.off1[1 + k] = s11 + k * N1;
            sd.X1[1 + k] = g + ((size_t)(2 * N0 + N1) + (size_t)k * N1) * H1;
        }
        spmm2_kernel<H1, true, false><<<(TR + 3) / 4, 256, 0, stream>>>(gptr, sd, cv, h0, h1, TR);
    }
    // layer 2 GEMMs (A = h0 / h1, bf16)
    {
        GemmB ga; ga.W[0] = W2_00; ga.cOff[0] = 0;
        ga.W[1] = W2_10; ga.cOff[1] = (long long)(N0 + N1) * H2;
        ga.W[2] = W2_00; ga.cOff[2] = 0; ga.W[3] = W2_00; ga.cOff[3] = 0;
        gemm_b_kernel<H1, H2, true><<<dim3((N0 * 4 + 255) / 256, 2), 256, 0, stream>>>(h0, ga, g, N0);
        GemmB gbt; gbt.W[0] = W2_01; gbt.cOff[0] = (long long)N0 * H2;
        for (int k = 0; k < K11; ++k) {
            gbt.W[1 + k] = W2_11 + (size_t)k * H1 * H2;
            gbt.cOff[1 + k] = ((long long)(2 * N0 + N1) + (long long)k * N1) * H2;
        }
        gemm_b_kernel<H1, H2, true><<<dim3((N1 * 4 + 255) / 256, 4), 256, 0, stream>>>(h1, gbt, g, N1);
    }
    // layer 2 SpMM (z0 + z1 fused, f32 out)
    {
        SpmmD sd;
        sd.n0 = N0; sd.nseg0 = 2; sd.nseg1 = 4;
        sd.off0[0] = s00; sd.X0[0] = g;
        sd.off0[1] = s01; sd.X0[1] = g + (size_t)N0 * H2;
        sd.off1[0] = s10; sd.X1[0] = g + (size_t)(N0 + N1) * H2;
        for (int k = 0; k < K11; ++k) {
            sd.off1[1 + k] = s11 + k * N1;
            sd.X1[1 + k] = g + ((size_t)(2 * N0 + N1) + (size_t)k * N1) * H2;
        }
        spmm2_kernel<H2, false, true><<<(TR + 3) / 4, 256, 0, stream>>>(gptr, sd, cv, z0, z1, TR);
    }

    (void)n_in; (void)out_size;
}

// Round 13
// 407.338 us; speedup vs baseline: 7.3252x; 1.0295x over previous
//
#include <hip/hip_runtime.h>
#include <hip/hip_bf16.h>

constexpr int F = 128, H1 = 64, H2 = 32, K11 = 3;
constexpr int BSH = 6;                 // 64 rows per bin
constexpr int PARTE = 4096;            // edges per partition block
constexpr int HISTE = 16384;           // edges per binhist block

// ---- bf16 helpers ----
static __device__ __forceinline__ float bf_lo(unsigned u) { return __uint_as_float(u << 16); }
static __device__ __forceinline__ float bf_hi(unsigned u) { return __uint_as_float(u & 0xffff0000u); }
static __device__ __forceinline__ unsigned bf16_1(float a) {     // low-16 bf16 (RNE)
    unsigned ua = __float_as_uint(a);
    return (ua + 0x7fffu + ((ua >> 16) & 1u)) >> 16;
}
static __device__ __forceinline__ unsigned pack_bf16(float a, float b) {
    unsigned ua = __float_as_uint(a), ub = __float_as_uint(b);
    unsigned ra = (ua + 0x7fffu + ((ua >> 16) & 1u)) >> 16;
    unsigned rb = (ub + 0x7fffu + ((ub >> 16) & 1u)) & 0xffff0000u;
    return ra | rb;
}

// ---------------- batched dense GEMM: C_y[M x HH](bf16) = A[M x FF] @ W_y[FF x HH] ----------------
struct GemmB { const float* W[4]; long long cOff[4]; };

template<int FF, int HH, bool ABF16>
__launch_bounds__(256)
__global__ void gemm_b_kernel(const void* __restrict__ Av, GemmB gb,
                              ushort* __restrict__ Cb, int M) {
    const float* __restrict__ W = gb.W[blockIdx.y];
    ushort* C = Cb + gb.cOff[blockIdx.y];
    __shared__ float Ws[FF * HH];
    const int tid = threadIdx.x;
    for (int i = tid * 4; i < FF * HH; i += 1024)
        *reinterpret_cast<float4*>(&Ws[i]) = *reinterpret_cast<const float4*>(&W[i]);
    __syncthreads();

    constexpr int TPR = 4;
    constexpr int CPT = HH / TPR;
    const int t = blockIdx.x * 256 + tid;
    const int row = t / TPR;
    const int sub = t % TPR;
    if (row >= M) return;

    float acc[CPT];
#pragma unroll
    for (int j = 0; j < CPT; ++j) acc[j] = 0.f;

    for (int k = 0; k < FF; k += 8) {
        float av[8];
        if (ABF16) {
            const uint4 u = *reinterpret_cast<const uint4*>((const ushort*)Av + (size_t)row * FF + k);
            av[0] = bf_lo(u.x); av[1] = bf_hi(u.x);
            av[2] = bf_lo(u.y); av[3] = bf_hi(u.y);
            av[4] = bf_lo(u.z); av[5] = bf_hi(u.z);
            av[6] = bf_lo(u.w); av[7] = bf_hi(u.w);
        } else {
            const float* A = (const float*)Av + (size_t)row * FF + k;
            const float4 u0 = *reinterpret_cast<const float4*>(A);
            const float4 u1 = *reinterpret_cast<const float4*>(A + 4);
            av[0] = u0.x; av[1] = u0.y; av[2] = u0.z; av[3] = u0.w;
            av[4] = u1.x; av[5] = u1.y; av[6] = u1.z; av[7] = u1.w;
        }
#pragma unroll
        for (int kk = 0; kk < 8; ++kk) {
            const float* wr = &Ws[(k + kk) * HH + sub * CPT];
#pragma unroll
            for (int j = 0; j < CPT; j += 4) {
                const float4 wv = *reinterpret_cast<const float4*>(&wr[j]);
                acc[j + 0] = fmaf(av[kk], wv.x, acc[j + 0]);
                acc[j + 1] = fmaf(av[kk], wv.y, acc[j + 1]);
                acc[j + 2] = fmaf(av[kk], wv.z, acc[j + 2]);
                acc[j + 3] = fmaf(av[kk], wv.w, acc[j + 3]);
            }
        }
    }
    unsigned packed[CPT / 2];
#pragma unroll
    for (int j = 0; j < CPT; j += 2) packed[j / 2] = pack_bf16(acc[j], acc[j + 1]);
    unsigned* c = (unsigned*)(C + (size_t)row * HH + sub * CPT);
#pragma unroll
    for (int j = 0; j < CPT / 2; j += 4)
        *reinterpret_cast<uint4*>(&c[j]) = make_uint4(packed[j], packed[j + 1], packed[j + 2], packed[j + 3]);
}

// ---------------- CSR build: two-level bin partition (64-row bins) ----------------
struct BinDesc { const int* rows[6]; int E[6]; int n[6]; int binBase[6]; };

__launch_bounds__(256)
__global__ void binhist_kernel(BinDesc d, int* __restrict__ binCnt) {
    const int a = blockIdx.y;
    const int E = d.E[a];
    const int start = blockIdx.x * HISTE;
    if (start >= E) return;
    const int nb = (d.n[a] + 63) >> BSH;        // <= 1024
    __shared__ int h[1024];
    for (int i = threadIdx.x; i < nb; i += 256) h[i] = 0;
    __syncthreads();
    const int* rows = d.rows[a];
    const int end = min(E, start + HISTE);
    for (int e = start + (int)threadIdx.x; e < end; e += 256)
        atomicAdd(&h[rows[e] >> BSH], 1);
    __syncthreads();
    int* bc = binCnt + d.binBase[a];
    for (int i = threadIdx.x; i < nb; i += 256)
        if (h[i]) atomicAdd(&bc[i], h[i]);
}

__launch_bounds__(256)
__global__ void binscan_kernel(const int* __restrict__ binCnt, int* __restrict__ binPtr,
                               int* __restrict__ binCur, int TB, int Etot,
                               int* __restrict__ gptr, int Lidx) {
    __shared__ int lds[256];
    __shared__ int carry;
    if (threadIdx.x == 0) carry = 0;
    __syncthreads();
    for (int base = 0; base < TB; base += 256) {
        const int i = base + threadIdx.x;
        const int v = (i < TB) ? binCnt[i] : 0;
        lds[threadIdx.x] = v;
        __syncthreads();
        for (int o = 1; o < 256; o <<= 1) {
            int t = (threadIdx.x >= o) ? lds[threadIdx.x - o] : 0;
            __syncthreads();
            lds[threadIdx.x] += t;
            __syncthreads();
        }
        const int c = carry;
        __syncthreads();
        if (i < TB) {
            const int excl = c + lds[threadIdx.x] - v;
            binPtr[i] = excl;
            binCur[i] = excl;
        }
        if (threadIdx.x == 255) carry = c + lds[255];
        __syncthreads();
    }
    if (threadIdx.x == 0) { binPtr[TB] = Etot; gptr[Lidx] = Etot; }
}

struct PartD {
    const int* rows[4]; const int* cols[4]; const float* vals[4];
    int E[4]; int nbins[4]; int binBase[4]; int edgeBase[4];
};

__launch_bounds__(256)
__global__ void partition_all_kernel(PartD d, int* __restrict__ binCur,
                                     uint2* __restrict__ tmp) {
    const int a = blockIdx.y;
    const int E = d.E[a];
    const int start = blockIdx.x * PARTE;
    if (start >= E) return;
    const int nbins = d.nbins[a];
    const int* __restrict__ rows = d.rows[a];
    const int* __restrict__ cols = d.cols[a];
    const float* __restrict__ vals = d.vals[a];
    int* __restrict__ bc = binCur + d.binBase[a];
    const int tmpBase = d.edgeBase[a];
    __shared__ int h[1024];
    __shared__ int base[1024];
    for (int i = threadIdx.x; i < nbins; i += 256) h[i] = 0;
    __syncthreads();
    int r[PARTE / 256];
#pragma unroll
    for (int j = 0; j < PARTE / 256; ++j) {
        const int idx = start + j * 256 + (int)threadIdx.x;
        r[j] = (idx < E) ? rows[idx] : -1;
        if (r[j] >= 0) atomicAdd(&h[r[j] >> BSH], 1);
    }
    __syncthreads();
    for (int i = threadIdx.x; i < nbins; i += 256) {
        const int c = h[i];
        base[i] = c ? atomicAdd(&bc[i], c) : 0;
    }
    __syncthreads();
    for (int i = threadIdx.x; i < nbins; i += 256) h[i] = 0;
    __syncthreads();
#pragma unroll
    for (int j = 0; j < PARTE / 256; ++j) {
        if (r[j] >= 0) {
            const int idx = start + j * 256 + (int)threadIdx.x;
            const int b = r[j] >> BSH;
            const int p = atomicAdd(&h[b], 1);
            tmp[(size_t)(base[b] + p - tmpBase)] =
                make_uint2(((unsigned)(r[j] & 63) << 16) | (unsigned)cols[idx],
                           __float_as_uint(vals[idx]));
        }
    }
}

struct FinD { int binBase[4]; int edgeBase[4]; int n[4]; int rowBase[4]; };

__launch_bounds__(256)
__global__ void finalize_all_kernel(FinD d, const uint2* __restrict__ tmp,
                                    const int* __restrict__ binPtr,
                                    int* __restrict__ gptr, unsigned* __restrict__ cv) {
    const int a = blockIdx.y;
    const int n = d.n[a];
    const int nbins = (n + 63) >> BSH;
    const int b = blockIdx.x;
    if (b >= nbins) return;
    const int* bp = binPtr + d.binBase[a];
    const int binStart = bp[b], binEnd = bp[b + 1];
    const int lo = binStart - d.edgeBase[a], hi = binEnd - d.edgeBase[a];
    __shared__ int cnt[64], off[64], cur[64];
    if (threadIdx.x < 64) cnt[threadIdx.x] = 0;
    __syncthreads();
    for (int i = lo + (int)threadIdx.x; i < hi; i += 256)
        atomicAdd(&cnt[tmp[i].x >> 16], 1);
    __syncthreads();
    if (threadIdx.x < 64) off[threadIdx.x] = cnt[threadIdx.x];
    __syncthreads();
    for (int o = 1; o < 64; o <<= 1) {
        int t = 0;
        if (threadIdx.x < 64 && (int)threadIdx.x >= o) t = off[threadIdx.x - o];
        __syncthreads();
        if (threadIdx.x < 64) off[threadIdx.x] += t;
        __syncthreads();
    }
    const int r0 = b << BSH;
    const int nrows = min(64, n - r0);
    if (threadIdx.x < 64) {
        const int excl = off[threadIdx.x] - cnt[threadIdx.x];
        cur[threadIdx.x] = excl;
        if ((int)threadIdx.x < nrows) (gptr + d.rowBase[a])[r0 + threadIdx.x] = binStart + excl;
    }
    __syncthreads();
    for (int i = lo + (int)threadIdx.x; i < hi; i += 256) {
        const uint2 t = tmp[i];
        const int p = atomicAdd(&cur[t.x >> 16], 1);
        cv[binStart + p] = ((t.x & 0xffffu) << 16) | bf16_1(__uint_as_float(t.y));
    }
}

// ---------------- SpMM v3: wave-per-row, 8B gathers, EPW edges in parallel ----------------
struct SpmmD {
    int n0, nseg0, nseg1;
    int off0[2], off1[4];
    const ushort* X0[2];
    const ushort* X1[4];
};

template<int HH, bool RELU, bool YF32>
__launch_bounds__(256)
__global__ void spmm2_kernel(const int* __restrict__ gptr, SpmmD d,
                             const unsigned* __restrict__ cv,
                             void* __restrict__ Y0, void* __restrict__ Y1,
                             int totalRows) {
    constexpr int LPR = HH / 4;        // lanes per row (uint2 = 4 bf16 each)
    constexpr int EPW = 64 / LPR;      // edges in parallel per wave (H1: 4, H2: 8)
    const int wid = (int)threadIdx.x >> 6;
    const int lane = (int)threadIdx.x & 63;
    const int sub = lane / LPR;        // edge slot
    const int c = lane % LPR;          // uint2 index within row
    const int grow = blockIdx.x * 4 + wid;
    if (grow >= totalRows) return;

    int row, nseg; void* Y;
    int o[4]; const uint2* X[4];
    if (grow < d.n0) {
        row = grow; Y = Y0; nseg = d.nseg0;
        o[0] = d.off0[0]; o[1] = d.off0[1]; o[2] = 0; o[3] = 0;
        X[0] = (const uint2*)d.X0[0]; X[1] = (const uint2*)d.X0[1];
        X[2] = nullptr; X[3] = nullptr;
    } else {
        row = grow - d.n0; Y = Y1; nseg = d.nseg1;
        o[0] = d.off1[0]; o[1] = d.off1[1]; o[2] = d.off1[2]; o[3] = d.off1[3];
        X[0] = (const uint2*)d.X1[0]; X[1] = (const uint2*)d.X1[1];
        X[2] = (const uint2*)d.X1[2]; X[3] = (const uint2*)d.X1[3];
    }

    float4 a0 = {0,0,0,0}, a1 = {0,0,0,0}, a2 = {0,0,0,0}, a3 = {0,0,0,0};
#pragma unroll
    for (int sg = 0; sg < 4; ++sg) {
        if (sg < nseg) {
            const int* p = gptr + o[sg] + row;
            const int s = p[0], e = p[1];
            const uint2* __restrict__ Xs = X[sg];
            int i = s;
            for (; i + 4 * EPW <= e; i += 4 * EPW) {
                const unsigned cw0 = cv[i + 0 * EPW + sub];
                const unsigned cw1 = cv[i + 1 * EPW + sub];
                const unsigned cw2 = cv[i + 2 * EPW + sub];
                const unsigned cw3 = cv[i + 3 * EPW + sub];
                const uint2 x0 = Xs[(size_t)(cw0 >> 16) * LPR + c];
                const uint2 x1 = Xs[(size_t)(cw1 >> 16) * LPR + c];
                const uint2 x2 = Xs[(size_t)(cw2 >> 16) * LPR + c];
                const uint2 x3 = Xs[(size_t)(cw3 >> 16) * LPR + c];
                const float v0 = __uint_as_float(cw0 << 16);
                const float v1 = __uint_as_float(cw1 << 16);
                const float v2 = __uint_as_float(cw2 << 16);
                const float v3 = __uint_as_float(cw3 << 16);
                a0.x = fmaf(v0, bf_lo(x0.x), a0.x); a0.y = fmaf(v0, bf_hi(x0.x), a0.y);
                a0.z = fmaf(v0, bf_lo(x0.y), a0.z); a0.w = fmaf(v0, bf_hi(x0.y), a0.w);
                a1.x = fmaf(v1, bf_lo(x1.x), a1.x); a1.y = fmaf(v1, bf_hi(x1.x), a1.y);
                a1.z = fmaf(v1, bf_lo(x1.y), a1.z); a1.w = fmaf(v1, bf_hi(x1.y), a1.w);
                a2.x = fmaf(v2, bf_lo(x2.x), a2.x); a2.y = fmaf(v2, bf_hi(x2.x), a2.y);
                a2.z = fmaf(v2, bf_lo(x2.y), a2.z); a2.w = fmaf(v2, bf_hi(x2.y), a2.w);
                a3.x = fmaf(v3, bf_lo(x3.x), a3.x); a3.y = fmaf(v3, bf_hi(x3.x), a3.y);
                a3.z = fmaf(v3, bf_lo(x3.y), a3.z); a3.w = fmaf(v3, bf_hi(x3.y), a3.w);
            }
#pragma unroll
            for (int j = 0; j < 4; ++j) {
                const int idx = i + j * EPW + sub;
                if (idx < e) {
                    const unsigned cw = cv[idx];
                    const uint2 x = Xs[(size_t)(cw >> 16) * LPR + c];
                    const float v = __uint_as_float(cw << 16);
                    a0.x = fmaf(v, bf_lo(x.x), a0.x); a0.y = fmaf(v, bf_hi(x.x), a0.y);
                    a0.z = fmaf(v, bf_lo(x.y), a0.z); a0.w = fmaf(v, bf_hi(x.y), a0.w);
                }
            }
        }
    }
    float4 r;
    r.x = (a0.x + a1.x) + (a2.x + a3.x);
    r.y = (a0.y + a1.y) + (a2.y + a3.y);
    r.z = (a0.z + a1.z) + (a2.z + a3.z);
    r.w = (a0.w + a1.w) + (a2.w + a3.w);
#pragma unroll
    for (int off = LPR; off < 64; off <<= 1) {
        r.x += __shfl_xor(r.x, off, 64);
        r.y += __shfl_xor(r.y, off, 64);
        r.z += __shfl_xor(r.z, off, 64);
        r.w += __shfl_xor(r.w, off, 64);
    }
    if (sub == 0) {
        if (RELU) {
            r.x = fmaxf(r.x, 0.f); r.y = fmaxf(r.y, 0.f);
            r.z = fmaxf(r.z, 0.f); r.w = fmaxf(r.w, 0.f);
        }
        if (YF32) {
            *reinterpret_cast<float4*>((float*)Y + (size_t)row * HH + c * 4) = r;
        } else {
            reinterpret_cast<uint2*>((unsigned*)Y + (size_t)row * (HH / 2))[c] =
                make_uint2(pack_bf16(r.x, r.y), pack_bf16(r.z, r.w));
        }
    }
}

extern "C" void kernel_launch(void* const* d_in, const int* in_sizes, int n_in,
                              void* d_out, int out_size, void* d_ws, size_t ws_size,
                              hipStream_t stream) {
    const float* feat0 = (const float*)d_in[0];
    const float* feat1 = (const float*)d_in[1];
    const int*   e00_row = (const int*)d_in[2];
    const int*   e00_col = (const int*)d_in[3];
    const float* e00_val = (const float*)d_in[4];
    const int*   e01_row = (const int*)d_in[5];
    const int*   e01_col = (const int*)d_in[6];
    const float* e01_val = (const float*)d_in[7];
    const int*   e10_row = (const int*)d_in[8];
    const int*   e10_col = (const int*)d_in[9];
    const float* e10_val = (const float*)d_in[10];
    const int*   e11_row = (const int*)d_in[11];
    const int*   e11_col = (const int*)d_in[12];
    const float* e11_val = (const float*)d_in[13];
    const float* W1_00 = (const float*)d_in[14];
    const float* W1_01 = (const float*)d_in[15];
    const float* W1_10 = (const float*)d_in[16];
    const float* W1_11 = (const float*)d_in[17];
    const float* W2_00 = (const float*)d_in[18];
    const float* W2_01 = (const float*)d_in[19];
    const float* W2_10 = (const float*)d_in[20];
    const float* W2_11 = (const float*)d_in[21];

    const int N0  = in_sizes[0] / F;
    const int N1  = in_sizes[1] / F;
    const int E00 = in_sizes[2];
    const int E01 = in_sizes[5];
    const int E10 = in_sizes[8];
    const int E11 = in_sizes[11] / K11;
    const long long E_total = (long long)E00 + E01 + E10 + (long long)K11 * E11;

    const int s00 = 0, s01 = N0, s10 = 2 * N0, s11 = 2 * N0 + N1;
    const int L = 2 * N0 + (1 + K11) * N1;

    struct HA { const int* rows; const int* cols; const float* vals; int E; int s; int n; };
    const HA arrs[6] = {
        {e00_row, e00_col, e00_val, E00, s00, N0},
        {e01_row, e01_col, e01_val, E01, s01, N0},
        {e10_row, e10_col, e10_val, E10, s10, N1},
        {e11_row,          e11_col,          e11_val,          E11, s11,          N1},
        {e11_row + E11,    e11_col + E11,    e11_val + E11,    E11, s11 + N1,     N1},
        {e11_row + 2*E11,  e11_col + 2*E11,  e11_val + 2*E11,  E11, s11 + 2*N1,   N1},
    };

    int nbins_[6], binBase_[6]; long long edgeBase_[6];
    int TB = 0; long long eb = 0;
    int maxE = 0;
    for (int i = 0; i < 6; ++i) {
        binBase_[i] = TB; nbins_[i] = (arrs[i].n + 63) >> BSH; TB += nbins_[i];
        edgeBase_[i] = eb; eb += arrs[i].E;
        maxE = max(maxE, arrs[i].E);
    }
    const int TBc = (TB + 2 + 3) & ~3;
    const int Lc = (L + 1 + 3) & ~3;

    // ---- workspace layout ----
    ushort* h0 = (ushort*)d_ws;                       // N0*H1 bf16
    ushort* h1 = h0 + (size_t)N0 * H1;                // N1*H1 bf16
    ushort* g  = h1 + (size_t)N1 * H1;                // (2N0+4N1)*H1 bf16 stage buffer (aliased by tmp)
    const size_t G = ((size_t)2 * N0 + 4 * N1) * H1;
    int* iw = (int*)(g + G);
    int* binCnt = iw;
    int* binPtr = binCnt + TBc;
    int* binCur = binPtr + TBc;
    int* gptr   = binCur + TBc;
    unsigned* cv = (unsigned*)(gptr + Lc);

    const size_t required = ((size_t)(N0 + N1) * H1 + G) * 2
                          + ((size_t)3 * TBc + Lc + (size_t)E_total) * 4;
    const size_t batchA = ((size_t)E00 + E01) * 8;
    const size_t batchB = ((size_t)E10 + (size_t)K11 * E11) * 8;
    if (ws_size < required || N0 > 65536 || N1 > 65536 ||
        batchA > G * 2 || batchB > G * 2) return;

    // -------- CSR build --------
    hipMemsetAsync(binCnt, 0, (size_t)TBc * sizeof(int), stream);
    BinDesc bd;
    for (int i = 0; i < 6; ++i) { bd.rows[i] = arrs[i].rows; bd.E[i] = arrs[i].E; bd.n[i] = arrs[i].n; bd.binBase[i] = binBase_[i]; }
    binhist_kernel<<<dim3((maxE + HISTE - 1) / HISTE, 6), 256, 0, stream>>>(bd, binCnt);
    binscan_kernel<<<1, 256, 0, stream>>>(binCnt, binPtr, binCur, TB, (int)E_total, gptr, L);

    uint2* tmp = (uint2*)g;
    auto launchPF = [&](int first, int cnt) {
        const long long tmpBase = edgeBase_[first];
        PartD pd{}; FinD fd{};
        int mE = 0, mNB = 0;
        for (int j = 0; j < cnt; ++j) {
            const int i = first + j;
            pd.rows[j] = arrs[i].rows; pd.cols[j] = arrs[i].cols; pd.vals[j] = arrs[i].vals;
            pd.E[j] = arrs[i].E; pd.nbins[j] = nbins_[i]; pd.binBase[j] = binBase_[i];
            pd.edgeBase[j] = (int)tmpBase;
            fd.binBase[j] = binBase_[i]; fd.edgeBase[j] = (int)tmpBase;
            fd.n[j] = arrs[i].n; fd.rowBase[j] = arrs[i].s;
            mE = max(mE, arrs[i].E); mNB = max(mNB, nbins_[i]);
        }
        partition_all_kernel<<<dim3((mE + PARTE - 1) / PARTE, cnt), 256, 0, stream>>>(pd, binCur, tmp);
        finalize_all_kernel<<<dim3(mNB, cnt), 256, 0, stream>>>(fd, tmp, binPtr, gptr, cv);
    };
    launchPF(0, 2);   // e00 + e01
    launchPF(2, 4);   // e10 + e11 x3

    // -------- main sequence --------
    float* z0 = (float*)d_out;
    float* z1 = (float*)d_out + (size_t)N0 * H2;
    const int TR = N0 + N1;

    // layer 1 GEMMs: g rows = [A(N0) | B(N1) | C(N0) | D0(N1) D1(N1) D2(N1)]
    {
        GemmB ga; ga.W[0] = W1_00; ga.cOff[0] = 0;
        ga.W[1] = W1_10; ga.cOff[1] = (long long)(N0 + N1) * H1;
        ga.W[2] = W1_00; ga.cOff[2] = 0; ga.W[3] = W1_00; ga.cOff[3] = 0;
        gemm_b_kernel<F, H1, false><<<dim3((N0 * 4 + 255) / 256, 2), 256, 0, stream>>>(feat0, ga, g, N0);
        GemmB gbt; gbt.W[0] = W1_01; gbt.cOff[0] = (long long)N0 * H1;
        for (int k = 0; k < K11; ++k) {
            gbt.W[1 + k] = W1_11 + (size_t)k * F * H1;
            gbt.cOff[1 + k] = ((long long)(2 * N0 + N1) + (long long)k * N1) * H1;
        }
        gemm_b_kernel<F, H1, false><<<dim3((N1 * 4 + 255) / 256, 4), 256, 0, stream>>>(feat1, gbt, g, N1);
    }
    // layer 1 SpMM (h0 + h1 fused)
    {
        SpmmD sd;
        sd.n0 = N0; sd.nseg0 = 2; sd.nseg1 = 4;
        sd.off0[0] = s00; sd.X0[0] = g;
        sd.off0[1] = s01; sd.X0[1] = g + (size_t)N0 * H1;
        sd.off1[0] = s10; sd.X1[0] = g + (size_t)(N0 + N1) * H1;
        for (int k = 0; k < K11; ++k) {
            sd.off1[1 + k] = s11 + k * N1;
            sd.X1[1 + k] = g + ((size_t)(2 * N0 + N1) + (size_t)k * N1) * H1;
        }
        spmm2_kernel<H1, true, false><<<(TR + 3) / 4, 256, 0, stream>>>(gptr, sd, cv, h0, h1, TR);
    }
    // layer 2 GEMMs (A = h0 / h1, bf16)
    {
        GemmB ga; ga.W[0] = W2_00; ga.cOff[0] = 0;
        ga.W[1] = W2_10; ga.cOff[1] = (long long)(N0 + N1) * H2;
        ga.W[2] = W2_00; ga.cOff[2] = 0; ga.W[3] = W2_00; ga.cOff[3] = 0;
        gemm_b_kernel<H1, H2, true><<<dim3((N0 * 4 + 255) / 256, 2), 256, 0, stream>>>(h0, ga, g, N0);
        GemmB gbt; gbt.W[0] = W2_01; gbt.cOff[0] = (long long)N0 * H2;
        for (int k = 0; k < K11; ++k) {
            gbt.W[1 + k] = W2_11 + (size_t)k * H1 * H2;
            gbt.cOff[1 + k] = ((long long)(2 * N0 + N1) + (long long)k * N1) * H2;
        }
        gemm_b_kernel<H1, H2, true><<<dim3((N1 * 4 + 255) / 256, 4), 256, 0, stream>>>(h1, gbt, g, N1);
    }
    // layer 2 SpMM (z0 + z1 fused, f32 out)
    {
        SpmmD sd;
        sd.n0 = N0; sd.nseg0 = 2; sd.nseg1 = 4;
        sd.off0[0] = s00; sd.X0[0] = g;
        sd.off0[1] = s01; sd.X0[1] = g + (size_t)N0 * H2;
        sd.off1[0] = s10; sd.X1[0] = g + (size_t)(N0 + N1) * H2;
        for (int k = 0; k < K11; ++k) {
            sd.off1[1 + k] = s11 + k * N1;
            sd.X1[1 + k] = g + ((size_t)(2 * N0 + N1) + (size_t)k * N1) * H2;
        }
        spmm2_kernel<H2, false, true><<<(TR + 3) / 4, 256, 0, stream>>>(gptr, sd, cv, z0, z1, TR);
    }

    (void)n_in; (void)out_size;
}